// Round 12
// baseline (6143.633 us; speedup 1.0000x reference)
//
#include <hip/hip_runtime.h>
#include <hip/hip_bf16.h>
#include <cstddef>

typedef __attribute__((ext_vector_type(8))) short bf16x8;
typedef __attribute__((ext_vector_type(4))) float f32x4;
typedef __attribute__((ext_vector_type(4))) unsigned int u32x4;

constexpr int kB = 64;      // batch
constexpr int kS = 1024;    // seq len
constexpr int kH = 512;     // hidden (== input size)
constexpr int kNBG = 4;     // batch groups (16 batches each)
constexpr int kHst = 520;   // padded LDS h-stage row stride (elems)
constexpr unsigned kSentB = 0xFFC0FFC0u;  // 2x bf16 NaN: impossible for real h
constexpr unsigned kSentF = 0xFFC00000u;  // f32 NaN: impossible for real h
constexpr int kPollCap = 1 << 13;         // per-stage retry cap (fail-fast)

__device__ __forceinline__ unsigned short f2bf(float f) {
  unsigned int u = __float_as_uint(f);
  u += 0x7FFFu + ((u >> 16) & 1u);   // round-to-nearest-even
  return (unsigned short)(u >> 16);
}

// ---------------- coherent (IF$) helpers: sc0 sc1 bypass L1+L2 ----------------
__device__ __forceinline__ void st_u64_coh(void* p, unsigned long long v) {
  asm volatile("global_store_dwordx2 %0, %1, off sc0 sc1" ::"v"(p), "v"(v) : "memory");
}
__device__ __forceinline__ void st_f32x4_coh(void* p, f32x4 v) {
  asm volatile("global_store_dwordx4 %0, %1, off sc0 sc1" ::"v"(p), "v"(v) : "memory");
}

#define COH_LD16(dst, p, OFF)                                             \
  asm volatile("global_load_dwordx4 %0, %1, off offset:" #OFF " sc0 sc1"  \
               : "=v"(dst) : "v"(p) : "memory")

__device__ __forceinline__ void wait_vm0(void) {
  asm volatile("s_waitcnt vmcnt(0)" ::: "memory");
  __builtin_amdgcn_sched_barrier(0);  // rule #18
}

// per-lane sentinel stage: retry own 64B bf16 slice until no NaN words
__device__ __forceinline__ int stage_bf16(const unsigned short* sp, bf16x8* tA) {
  for (int r = 0; r < kPollCap; ++r) {
    COH_LD16(tA[0], sp, 0);  COH_LD16(tA[1], sp, 16);
    COH_LD16(tA[2], sp, 32); COH_LD16(tA[3], sp, 48);
    wait_vm0();
    int stale = 0;
#pragma unroll
    for (int i = 0; i < 4; ++i) {
      u32x4 w = *(const u32x4*)&tA[i];
      stale |= (w[0] == kSentB) | (w[1] == kSentB) | (w[2] == kSentB) | (w[3] == kSentB);
    }
    if (!stale) return 1;
  }
  return 0;
}

// pack 8 f32 -> bf16x8 via v_cvt_pk_bf16_f32 (RNE)
__device__ __forceinline__ bf16x8 pk_bf16(f32x4 lo, f32x4 hi) {
  union { u32x4 u; bf16x8 h; } r;
  asm("v_cvt_pk_bf16_f32 %0, %1, %2" : "=v"(r.u[0]) : "v"(lo[0]), "v"(lo[1]));
  asm("v_cvt_pk_bf16_f32 %0, %1, %2" : "=v"(r.u[1]) : "v"(lo[2]), "v"(lo[3]));
  asm("v_cvt_pk_bf16_f32 %0, %1, %2" : "=v"(r.u[2]) : "v"(hi[0]), "v"(hi[1]));
  asm("v_cvt_pk_bf16_f32 %0, %1, %2" : "=v"(r.u[3]) : "v"(hi[2]), "v"(hi[3]));
  return r.h;
}

// per-lane sentinel stage of 128B fp32 slice (32 f32) -> 4x bf16x8
__device__ __forceinline__ int stage_f32(const float* sp, bf16x8* o) {
  f32x4 v[8];
  for (int r = 0; r < kPollCap; ++r) {
    COH_LD16(v[0], sp, 0);   COH_LD16(v[1], sp, 16);
    COH_LD16(v[2], sp, 32);  COH_LD16(v[3], sp, 48);
    COH_LD16(v[4], sp, 64);  COH_LD16(v[5], sp, 80);
    COH_LD16(v[6], sp, 96);  COH_LD16(v[7], sp, 112);
    wait_vm0();
    int stale = 0;
#pragma unroll
    for (int i = 0; i < 8; ++i) {
      u32x4 w = *(const u32x4*)&v[i];
      stale |= (w[0] == kSentF) | (w[1] == kSentF) | (w[2] == kSentF) | (w[3] == kSentF);
    }
    if (!stale) {
#pragma unroll
      for (int j = 0; j < 4; ++j) o[j] = pk_bf16(v[2 * j], v[2 * j + 1]);
      return 1;
    }
  }
  return 0;
}

// ---------------- sentinel fills ----------------
__global__ void fill32(unsigned int* __restrict__ p, unsigned int v, int n) {
  int i = blockIdx.x * blockDim.x + threadIdx.x;
  if (i < n) p[i] = v;
}

// ---------------- fp32 -> bf16 converts ----------------
__global__ void cvt_f32_bf16(const float* __restrict__ in,
                             unsigned short* __restrict__ out, int n4) {
  int i = blockIdx.x * blockDim.x + threadIdx.x;
  if (i >= n4) return;
  float4 v = ((const float4*)in)[i];
  ushort4 o;
  o.x = f2bf(v.x); o.y = f2bf(v.y); o.z = f2bf(v.z); o.w = f2bf(v.w);
  ((ushort4*)out)[i] = o;
}

// x [B][S][I] fp32 -> xbf [S][B][I] bf16 (time-major)
__global__ void cvt_x_t(const float* __restrict__ in,
                        unsigned short* __restrict__ out, int n4) {
  int i4 = blockIdx.x * blockDim.x + threadIdx.x;
  if (i4 >= n4) return;
  int d = i4 * 4;
  int i = d & (kH - 1);
  int rem = d / kH;
  int b = rem & (kB - 1);
  int s = rem / kB;
  float4 v = *(const float4*)(in + ((size_t)b * kS + s) * kH + i);
  ushort4 o;
  o.x = f2bf(v.x); o.y = f2bf(v.y); o.z = f2bf(v.z); o.w = f2bf(v.w);
  *(ushort4*)(out + (size_t)d) = o;
}

// ---------------- fused persistent 2-layer GRU, sentinel-staged ----------------
// R11 partition: 256 WGs = layer (wgid>>7) x bg (wgid&3, 16 batches) x
// ug ((wgid&127)>>2, 16 units). NO flags/drains: publish = write-through
// sc0sc1 stores; consumers sentinel-poll exactly the bytes they stage
// (NaN = not yet written this launch). L1 self-recurrence polls fp32 h
// directly from `out` (per-t unique addresses -> sentinel-safe).
__launch_bounds__(256, 1)
__global__ void gru_fused(const unsigned short* __restrict__ xbf,   // [S][B][H]
                          const unsigned short* __restrict__ wih0,  // [3H][H]
                          const unsigned short* __restrict__ whh0,
                          const unsigned short* __restrict__ wih1,
                          const unsigned short* __restrict__ whh1,
                          const float* __restrict__ bih0, const float* __restrict__ bhh0,
                          const float* __restrict__ bih1, const float* __restrict__ bhh1,
                          unsigned short* __restrict__ hs0,    // [S][B][H] bf16
                          float* __restrict__ out) {           // [B][S][H]+[2][B][H]
  const int tid  = threadIdx.x;
  const int lane = tid & 63;
  const int wv   = tid >> 6;                  // wave 0..3
  const int wgid = blockIdx.x;
  const int layer = wgid >> 7;
  const int bg    = wgid & 3;                 // batch group
  const int ug    = (wgid & 127) >> 2;        // unit group
  const int bgb0  = bg * 16;
  const int j0w   = ug * 16 + wv * 4;         // this wave's 4 units

  const unsigned short* wih = layer ? wih1 : wih0;
  const unsigned short* whh = layer ? whh1 : whh0;
  const float* bih = layer ? bih1 : bih0;
  const float* bhh = layer ? bhh1 : bhh0;

  // ---- B-fragments (12 gate rows of this wave's 4 units) in VGPRs ----
  bf16x8 bx[16], bh[16];
  {
    const int n = lane & 15, hi = lane >> 4;
    if (n < 12) {
      const int orig = (n >> 2) * kH + j0w + (n & 3);  // gate*512 + unit
      const unsigned short* pX = wih + (size_t)orig * kH + hi * 8;
      const unsigned short* pH = whh + (size_t)orig * kH + hi * 8;
#pragma unroll
      for (int kk = 0; kk < 16; ++kk) {
        bx[kk] = *(const bf16x8*)(pX + kk * 32);
        bh[kk] = *(const bf16x8*)(pH + kk * 32);
      }
    } else {
      bf16x8 z = {0, 0, 0, 0, 0, 0, 0, 0};
#pragma unroll
      for (int kk = 0; kk < 16; ++kk) { bx[kk] = z; bh[kk] = z; }
    }
  }

  // gate thread mapping: thread -> (batch gb in group, unit guu 0..15)
  const int gb  = tid & 15;
  const int guu = tid >> 4;
  const int unit = ug * 16 + guu;
  const float bihr = bih[unit], bihz = bih[kH + unit], bihn = bih[2 * kH + unit];
  const float bhhr = bhh[unit], bhhz = bhh[kH + unit], bhhn = bhh[2 * kH + unit];
  float hprev = 0.0f;

  __shared__ unsigned short hA[16][kHst];  // staged h_{t-1}[16 batches][512]
  __shared__ unsigned short hX[16][kHst];  // staged hs0[t] (layer 1 only)
  __shared__ float gxl[16][52];            // exchange: 4 waves x 12 cols
  __shared__ float ghl[16][52];
  __shared__ unsigned short hl[16][20];    // padded gather for publish
  __shared__ float hlf[16][20];

  // A-fragment lane coords (M = 16 batches of this group)
  const int n_  = lane & 15;
  const int ahi = (lane >> 4) * 8;
  // bf16 stage coords: lane -> (row, 32-elem segment)
  const int srow  = lane & 15;
  const int scol0 = wv * 128 + (lane >> 4) * 32;
  // fp32 stage coords: thread -> (row, 32-f32 segment 0..15)
  const int fseg  = wv * 4 + (lane >> 4);

  for (int t = 0; t < kS; ++t) {
    // ---- layer 0: input GEMM pre-stage (x L2-cached, dependency-free) ----
    f32x4 accx = {0.f, 0.f, 0.f, 0.f};
    if (layer == 0) {
      const unsigned short* pAX = xbf + ((size_t)t * kB + bgb0 + n_) * kH + ahi;
#pragma unroll
      for (int kk = 0; kk < 16; ++kk) {
        bf16x8 ax = *(const bf16x8*)(pAX + kk * 32);
        accx = __builtin_amdgcn_mfma_f32_16x16x32_bf16(ax, bx[kk], accx, 0, 0, 0);
      }
    }

    // ---- sentinel-staged h loads (the load IS the sync) ----
    int ok = 1;
    if (t > 0) {
      if (layer == 0) {
        bf16x8 tA[4];
        ok &= stage_bf16(hs0 + ((size_t)(t - 1) * kB + bgb0 + srow) * kH + scol0, tA);
#pragma unroll
        for (int it = 0; it < 4; ++it)
          *(bf16x8*)&hA[srow][scol0 + it * 8] = tA[it];
      } else {
        bf16x8 tA[4];
        const float* sp = out + ((size_t)(bgb0 + srow) * kS + (t - 1)) * kH + fseg * 32;
        ok &= stage_f32(sp, tA);
#pragma unroll
        for (int it = 0; it < 4; ++it)
          *(bf16x8*)&hA[srow][fseg * 32 + it * 8] = tA[it];
      }
    }
    if (layer == 1) {
      bf16x8 tX[4];
      ok &= stage_bf16(hs0 + ((size_t)t * kB + bgb0 + srow) * kH + scol0, tX);
#pragma unroll
      for (int it = 0; it < 4; ++it)
        *(bf16x8*)&hX[srow][scol0 + it * 8] = tX[it];
    }
    if (!__syncthreads_and(ok)) return;  // fail-fast bail (output stays NaN)

    // ---- GEMMs from LDS stage ----
    if (layer == 1) {
#pragma unroll
      for (int kk = 0; kk < 16; ++kk) {
        bf16x8 axv = *(const bf16x8*)&hX[n_][kk * 32 + ahi];
        accx = __builtin_amdgcn_mfma_f32_16x16x32_bf16(axv, bx[kk], accx, 0, 0, 0);
      }
    }
    f32x4 acch = {0.f, 0.f, 0.f, 0.f};
    if (t > 0) {
#pragma unroll
      for (int kk = 0; kk < 16; ++kk) {
        bf16x8 ahv = *(const bf16x8*)&hA[n_][kk * 32 + ahi];
        acch = __builtin_amdgcn_mfma_f32_16x16x32_bf16(ahv, bh[kk], acch, 0, 0, 0);
      }
    }
    // exchange write: C row m=(lane>>4)*4+r (batch), col wv*12 + n (gate-row)
    if (n_ < 12) {
      const int m0 = (lane >> 4) * 4;
#pragma unroll
      for (int r = 0; r < 4; ++r) {
        gxl[m0 + r][wv * 12 + n_] = accx[r];
        ghl[m0 + r][wv * 12 + n_] = acch[r];
      }
    }
    __syncthreads();

    // ---- gates: thread (gb, guu); source wave uw = guu>>2, du = guu&3 ----
    {
      const int c0 = (guu >> 2) * 12, du = guu & 3;
      const float xr = gxl[gb][c0 + du]     + bihr;
      const float xz = gxl[gb][c0 + 4 + du] + bihz;
      const float xn = gxl[gb][c0 + 8 + du] + bihn;
      const float hr = ghl[gb][c0 + du]     + bhhr;
      const float hzv = ghl[gb][c0 + 4 + du] + bhhz;
      const float hn = ghl[gb][c0 + 8 + du] + bhhn;
      const float r = 1.0f / (1.0f + __expf(-(xr + hr)));
      const float z = 1.0f / (1.0f + __expf(-(xz + hzv)));
      const float nn = tanhf(xn + r * hn);
      const float hnew = (1.0f - z) * nn + z * hprev;
      hprev = hnew;
      hl[gb][guu] = f2bf(hnew);
      if (layer == 1) hlf[gb][guu] = hnew;
      if (t == kS - 1)  // h_n epilogue (plain store, flushed at kernel end)
        out[(size_t)kB * kS * kH + (size_t)layer * kB * kH +
            (size_t)(bgb0 + gb) * kH + unit] = hnew;
    }
    __syncthreads();

    // ---- publish: write-through sc0sc1 stores; NO drain, NO flags ----
    if (layer == 0) {
      if (tid < 64) {
        const int b = tid >> 2, q = tid & 3;
        unsigned long long pk = *(const unsigned long long*)&hl[b][q * 4];
        st_u64_coh(hs0 + ((size_t)t * kB + bgb0 + b) * kH + ug * 16 + q * 4, pk);
      }
    } else {
      if (tid < 64) {
        const int b = tid >> 2, q = tid & 3;
        st_f32x4_coh(out + ((size_t)(bgb0 + b) * kS + t) * kH + ug * 16 + q * 4,
                     *(const f32x4*)&hlf[b][q * 4]);  // [b][t][h]
      }
    }
    // no trailing barrier: next iteration's LDS writes sit behind the next
    // stage/exchange barriers, which the publishing wave joins after issuing.
  }
}

extern "C" void kernel_launch(void* const* d_in, const int* in_sizes, int n_in,
                              void* d_out, int out_size, void* d_ws, size_t ws_size,
                              hipStream_t stream) {
  const float* x     = (const float*)d_in[0];
  const float* w_ih0 = (const float*)d_in[1];
  const float* w_hh0 = (const float*)d_in[2];
  const float* b_ih0 = (const float*)d_in[3];
  const float* b_hh0 = (const float*)d_in[4];
  const float* w_ih1 = (const float*)d_in[5];
  const float* w_hh1 = (const float*)d_in[6];
  const float* b_ih1 = (const float*)d_in[7];
  const float* b_hh1 = (const float*)d_in[8];
  float* out = (float*)d_out;

  // ---- workspace layout (ushort elems unless noted) ----
  unsigned short* ws = (unsigned short*)d_ws;
  const size_t nX = (size_t)kB * kS * kH;   // 33,554,432
  const size_t nW = (size_t)3 * kH * kH;    // 786,432
  unsigned short* xbf   = ws;
  unsigned short* wih0b = xbf + nX;
  unsigned short* whh0b = wih0b + nW;
  unsigned short* wih1b = whh0b + nW;
  unsigned short* whh1b = wih1b + nW;
  unsigned short* hs0   = whh1b + nW;       // nX elems

  // sentinel pre-fills each launch (stale prior-replay data must read NaN)
  {
    int nh = (int)(nX / 2);                      // hs0 as u32
    fill32<<<(nh + 255) / 256, 256, 0, stream>>>((unsigned int*)hs0, kSentB, nh);
    int no = (int)nX;                            // out[B][S][H] as u32
    fill32<<<(no + 255) / 256, 256, 0, stream>>>((unsigned int*)out, kSentF, no);
  }
  // converts
  {
    int n4 = (int)(nX / 4);
    cvt_x_t<<<n4 / 256, 256, 0, stream>>>(x, xbf, n4);
    int w4 = (int)(nW / 4);
    cvt_f32_bf16<<<w4 / 256, 256, 0, stream>>>(w_ih0, wih0b, w4);
    cvt_f32_bf16<<<w4 / 256, 256, 0, stream>>>(w_hh0, whh0b, w4);
    cvt_f32_bf16<<<w4 / 256, 256, 0, stream>>>(w_ih1, wih1b, w4);
    cvt_f32_bf16<<<w4 / 256, 256, 0, stream>>>(w_hh1, whh1b, w4);
  }

  // fused persistent GRU — 256 blocks (all co-resident, 1/CU)
  gru_fused<<<dim3(256), dim3(256), 0, stream>>>(
      xbf, wih0b, whh0b, wih1b, whh1b,
      b_ih0, b_hh0, b_ih1, b_hh1,
      hs0, out);
}